// Round 9
// baseline (398.965 us; speedup 1.0000x reference)
//
#include <hip/hip_runtime.h>
#include <math.h>

#define NN 100000
#define KHID 128
#define KCLS 40
#define LN_EPS 1e-5f
#define NBKT ((NN + 255) >> 8)     // 391 buckets of 256 dst nodes
#define PCHUNK 4096                // edges per partition workgroup
#define BSTRIDE 5120               // slack bucket capacity (mean 4093, +16 sigma)

typedef unsigned short bfu;
typedef __attribute__((ext_vector_type(8))) short short8;
typedef __attribute__((ext_vector_type(4))) float floatx4;
typedef __attribute__((ext_vector_type(2))) float f32x2;

// float -> bf16 (RNE)
__device__ __forceinline__ bfu f2b(float f) {
    unsigned u = __float_as_uint(f);
    u += 0x7fffu + ((u >> 16) & 1u);
    return (bfu)(u >> 16);
}
__device__ __forceinline__ unsigned pack2(float a, float b) {
    return (unsigned)f2b(a) | ((unsigned)f2b(b) << 16);
}
// 8 bf16 in a uint4: unpack + packed FMA into 4 float2 accumulators
__device__ __forceinline__ void fma8p(uint4 v, float w, f32x2* a) {
    f32x2 w2; w2.x = w; w2.y = w;
    f32x2 p;
    p.x = __uint_as_float(v.x << 16); p.y = __uint_as_float(v.x & 0xffff0000u);
    a[0] = __builtin_elementwise_fma(p, w2, a[0]);
    p.x = __uint_as_float(v.y << 16); p.y = __uint_as_float(v.y & 0xffff0000u);
    a[1] = __builtin_elementwise_fma(p, w2, a[1]);
    p.x = __uint_as_float(v.z << 16); p.y = __uint_as_float(v.z & 0xffff0000u);
    a[2] = __builtin_elementwise_fma(p, w2, a[2]);
    p.x = __uint_as_float(v.w << 16); p.y = __uint_as_float(v.w & 0xffff0000u);
    a[3] = __builtin_elementwise_fma(p, w2, a[3]);
}

// ======================= CSR build (3 kernels, no global scan) =======================
__global__ __launch_bounds__(256) void k_binit(int* __restrict__ btail) {
    int b = blockIdx.x * 256 + threadIdx.x;
    if (b < NBKT) btail[b] = b * BSTRIDE;
}

// partition edges into slack dst-buckets; ebuf[pos] = (dst&255)<<20 | src
__global__ __launch_bounds__(256) void k_part(const int* __restrict__ srcA,
                                              const int* __restrict__ dstA,
                                              int* __restrict__ btail,
                                              int* __restrict__ ebuf, int E) {
    __shared__ int hist[NBKT];
    int tid = threadIdx.x;
    int base = blockIdx.x * PCHUNK;
    int sreg[PCHUNK / 256], dreg[PCHUNK / 256];

    for (int k = tid; k < NBKT; k += 256) hist[k] = 0;
    __syncthreads();
#pragma unroll
    for (int j = 0; j < PCHUNK / 256; j++) {
        int e = base + j * 256 + tid;
        if (e < E) {
            sreg[j] = srcA[e];
            int d = dstA[e];
            dreg[j] = d;
            atomicAdd(&hist[d >> 8], 1);
        } else dreg[j] = -1;
    }
    __syncthreads();
    for (int k = tid; k < NBKT; k += 256)
        hist[k] = atomicAdd(&btail[k], hist[k]);   // hist -> global cursor base
    __syncthreads();
#pragma unroll
    for (int j = 0; j < PCHUNK / 256; j++) {
        int d = dreg[j];
        if (d >= 0) {
            int pos = atomicAdd(&hist[d >> 8], 1);
            ebuf[pos] = ((d & 255) << 20) | sreg[j];
        }
    }
}

// per bucket: LDS count -> LDS scan -> rr/dinv/sorted col (all local, no global atomics)
__global__ __launch_bounds__(256) void k_csr(const int* __restrict__ ebuf,
                                             const int* __restrict__ btail,
                                             int2* __restrict__ rr,
                                             int* __restrict__ col,
                                             float* __restrict__ dinv) {
    __shared__ int lcnt[256];
    __shared__ int lcur[256];
    __shared__ int wtot[4];
    int b = blockIdx.x, tid = threadIdx.x;
    int basee = b * BSTRIDE;
    int bend  = btail[b];                 // end cursor after k_part
    lcnt[tid] = 0;
    __syncthreads();
    for (int e = basee + tid; e < bend; e += 256)
        atomicAdd(&lcnt[ebuf[e] >> 20], 1);
    __syncthreads();
    int v = lcnt[tid];
    int lane = tid & 63, wv = tid >> 6;
    int s = v;
#pragma unroll
    for (int off = 1; off < 64; off <<= 1) {
        int u = __shfl_up(s, off);
        if (lane >= off) s += u;
    }
    if (lane == 63) wtot[wv] = s;
    __syncthreads();
    int woff = 0;
    for (int w = 0; w < wv; w++) woff += wtot[w];
    int incl = woff + s;                  // inclusive prefix over the 256 local nodes
    int gi = (b << 8) + tid;
    if (gi < NN) {
        rr[gi] = make_int2(basee + incl - v, basee + incl);
        dinv[gi] = rsqrtf((float)(1 + v));
    }
    lcur[tid] = basee + incl - v;
    __syncthreads();
    for (int e = basee + tid; e < bend; e += 256) {
        int p = ebuf[e];
        int pos = atomicAdd(&lcur[p >> 20], 1);
        col[pos] = p & 0xFFFFF;
    }
}

// ===== MFMA GEMM: C[M,KOUT](bf16) = A[M,128] @ W[128,KOUT](f32); A bf16 or f32 ======
template <int KOUT, int NPAD, bool F32A>
__global__ __launch_bounds__(256) void k_gemm_mfma(const void* __restrict__ Av,
                                                   const float* __restrict__ W,
                                                   bfu* __restrict__ C, int M) {
    constexpr int NT = NPAD / 16;
    __shared__ bfu As[128][136];    // [m][k], +8 pad
    __shared__ bfu Ws[NPAD][136];   // [n][k] transposed, +8 pad

    int tid  = threadIdx.x;
    int row0 = blockIdx.x * 128;

    if constexpr (F32A) {
        // fp32 A: 64 KB tile, cvt to bf16 on LDS store (fuses the cast kernel)
        const float* Af = (const float*)Av + (size_t)row0 * 128;
#pragma unroll
        for (int c2 = 0; c2 < 16; c2++) {
            int off = c2 * 1024 + tid * 4;   // float index
            int r   = off >> 7;
            int kk  = off & 127;
            float4 f = (row0 + r < M) ? *(const float4*)(Af + off)
                                      : make_float4(0.f, 0.f, 0.f, 0.f);
            uint2 pv;
            pv.x = pack2(f.x, f.y);
            pv.y = pack2(f.z, f.w);
            *(uint2*)&As[r][kk] = pv;
        }
    } else {
        const char* Ab = (const char*)Av + (size_t)row0 * 256;
#pragma unroll
        for (int c2 = 0; c2 < 8; c2++) {
            int off = c2 * 4096 + tid * 16;  // byte offset in 32 KB tile
            int r   = off >> 8;
            int kb  = off & 255;
            uint4 v = *(const uint4*)(Ab + off);
            *(uint4*)((char*)&As[0][0] + r * 272 + kb) = v;
        }
    }
    // stage W transposed + cvt bf16
    if constexpr (KOUT == 128) {
        int n = tid & 127, kh = (tid >> 7) * 64;
#pragma unroll
        for (int kk = 0; kk < 64; kk += 8) {
            float f[8];
#pragma unroll
            for (int i = 0; i < 8; i++) f[i] = W[(size_t)(kh + kk + i) * 128 + n];
            uint4 v;
            v.x = pack2(f[0], f[1]); v.y = pack2(f[2], f[3]);
            v.z = pack2(f[4], f[5]); v.w = pack2(f[6], f[7]);
            *(uint4*)&Ws[n][kh + kk] = v;
        }
    } else {
        int n = tid & 63, kh = (tid >> 6) * 32;
        if (n < NPAD) {
#pragma unroll
            for (int kk = 0; kk < 32; kk += 8) {
                float f[8];
#pragma unroll
                for (int i = 0; i < 8; i++)
                    f[i] = (n < KOUT) ? W[(size_t)(kh + kk + i) * KOUT + n] : 0.f;
                uint4 v;
                v.x = pack2(f[0], f[1]); v.y = pack2(f[2], f[3]);
                v.z = pack2(f[4], f[5]); v.w = pack2(f[6], f[7]);
                *(uint4*)&Ws[n][kh + kk] = v;
            }
        }
    }
    __syncthreads();

    int w = tid >> 6, lane = tid & 63;
    int quad = lane >> 4, mrow = lane & 15;

    floatx4 acc[2][NT];
#pragma unroll
    for (int mt = 0; mt < 2; mt++)
#pragma unroll
        for (int nt = 0; nt < NT; nt++) acc[mt][nt] = (floatx4){0.f, 0.f, 0.f, 0.f};

#pragma unroll
    for (int ks = 0; ks < 4; ks++) {
        int ko = ks * 32 + quad * 8;
        short8 af[2];
#pragma unroll
        for (int mt = 0; mt < 2; mt++)
            af[mt] = *(const short8*)&As[16 * (2 * w + mt) + mrow][ko];
#pragma unroll
        for (int nt = 0; nt < NT; nt++) {
            short8 bf = *(const short8*)&Ws[16 * nt + mrow][ko];
#pragma unroll
            for (int mt = 0; mt < 2; mt++)
                acc[mt][nt] = __builtin_amdgcn_mfma_f32_16x16x32_bf16(af[mt], bf, acc[mt][nt], 0, 0, 0);
        }
    }

    // epilogue: C/D layout col=lane&15, row=quad*4+reg
#pragma unroll
    for (int mt = 0; mt < 2; mt++) {
        int rbase = row0 + 16 * (2 * w + mt) + quad * 4;
#pragma unroll
        for (int nt = 0; nt < NT; nt++) {
            int cidx = 16 * nt + mrow;
            if (KOUT != NPAD && cidx >= KOUT) continue;
#pragma unroll
            for (int r = 0; r < 4; r++) {
                int row = rbase + r;
                if (row < M) C[(size_t)row * KOUT + cidx] = f2b(acc[mt][nt][r]);
            }
        }
    }
}

// ======= fused gather + bias + LN + ReLU (K=128), wave/node, LDS (c,w) table =======
__global__ __launch_bounds__(256) void k_gather_ln(const bfu* __restrict__ hb,
                                                   const int2* __restrict__ rr,
                                                   const int* __restrict__ col,
                                                   const float* __restrict__ dinv,
                                                   const float* __restrict__ bias,
                                                   const float* __restrict__ gamma,
                                                   const float* __restrict__ beta,
                                                   bfu* __restrict__ outb) {
    __shared__ int2 tbl[4][64];
    int wv   = threadIdx.x >> 6;
    int lane = threadIdx.x & 63;
    int i = blockIdx.x * 4 + wv;
    if (i >= NN) return;
    int2 se = rr[i];
    int start = se.x, end = se.y;
    float di = dinv[i];
    int eq = lane >> 4;          // edge slot 0..3
    int fv = (lane & 15) * 8;    // feature base

    f32x2 a[4];
#pragma unroll
    for (int j = 0; j < 4; j++) { a[j].x = 0.f; a[j].y = 0.f; }
    if (eq == 0) {               // self-loop
        uint4 v = *(const uint4*)(hb + (size_t)i * 128 + fv);
        fma8p(v, di * di, a);
    }

    for (int b = start; b < end; b += 64) {
        int n = end - b; if (n > 64) n = 64;
        int2 cw;
        if (lane < n) {
            int c = col[b + lane];
            cw = make_int2(c, __float_as_int(dinv[c] * di));   // weight pre-multiplied
        } else cw = make_int2(0, 0);
        tbl[wv][lane] = cw;
        __builtin_amdgcn_wave_barrier();   // DS pipe is in-order per wave
        int tmax = (n + 3) >> 2;
        int t = 0;
        for (; t + 2 <= tmax; t += 2) {
            int2 e0 = tbl[wv][4 * t + eq];
            int2 e1 = tbl[wv][4 * t + 4 + eq];
            uint4 v0 = *(const uint4*)(hb + (size_t)e0.x * 128 + fv);
            uint4 v1 = *(const uint4*)(hb + (size_t)e1.x * 128 + fv);
            fma8p(v0, __int_as_float(e0.y), a);
            fma8p(v1, __int_as_float(e1.y), a);
        }
        if (t < tmax) {
            int2 e0 = tbl[wv][4 * t + eq];
            uint4 v0 = *(const uint4*)(hb + (size_t)e0.x * 128 + fv);
            fma8p(v0, __int_as_float(e0.y), a);
        }
        __builtin_amdgcn_wave_barrier();   // before next batch overwrites tbl
    }
    // merge the 4 edge slots
    float x[8];
    x[0]=a[0].x; x[1]=a[0].y; x[2]=a[1].x; x[3]=a[1].y;
    x[4]=a[2].x; x[5]=a[2].y; x[6]=a[3].x; x[7]=a[3].y;
#pragma unroll
    for (int j = 0; j < 8; j++) {
        x[j] += __shfl_xor(x[j], 16);
        x[j] += __shfl_xor(x[j], 32);
    }

    float4 bb0 = *(const float4*)(bias + fv);
    float4 bb1 = *(const float4*)(bias + fv + 4);
    x[0]+=bb0.x; x[1]+=bb0.y; x[2]+=bb0.z; x[3]+=bb0.w;
    x[4]+=bb1.x; x[5]+=bb1.y; x[6]+=bb1.z; x[7]+=bb1.w;

    float s = x[0]+x[1]+x[2]+x[3]+x[4]+x[5]+x[6]+x[7];
#pragma unroll
    for (int m = 1; m < 16; m <<= 1) s += __shfl_xor(s, m);   // 16 groups -> full sum
    float mu = s * (1.f / 128.f);
    float d[8], vs = 0.f;
#pragma unroll
    for (int j = 0; j < 8; j++) { d[j] = x[j] - mu; vs += d[j] * d[j]; }
#pragma unroll
    for (int m = 1; m < 16; m <<= 1) vs += __shfl_xor(vs, m);
    float inv = rsqrtf(vs * (1.f / 128.f) + LN_EPS);
    if (eq == 0) {
        float4 gg0 = *(const float4*)(gamma + fv);
        float4 gg1 = *(const float4*)(gamma + fv + 4);
        float4 ee0 = *(const float4*)(beta + fv);
        float4 ee1 = *(const float4*)(beta + fv + 4);
        uint4 o;
        o.x = pack2(fmaxf(d[0]*inv*gg0.x + ee0.x, 0.f), fmaxf(d[1]*inv*gg0.y + ee0.y, 0.f));
        o.y = pack2(fmaxf(d[2]*inv*gg0.z + ee0.z, 0.f), fmaxf(d[3]*inv*gg0.w + ee0.w, 0.f));
        o.z = pack2(fmaxf(d[4]*inv*gg1.x + ee1.x, 0.f), fmaxf(d[5]*inv*gg1.y + ee1.y, 0.f));
        o.w = pack2(fmaxf(d[6]*inv*gg1.z + ee1.z, 0.f), fmaxf(d[7]*inv*gg1.w + ee1.w, 0.f));
        *(uint4*)(outb + (size_t)i * 128 + fv) = o;
    }
}

// ===== fused gather + bias + log_softmax (K=40), wave/node, LDS (c,w) table =====
__global__ __launch_bounds__(256) void k_gather_lsm(const bfu* __restrict__ hb,
                                                    const int2* __restrict__ rr,
                                                    const int* __restrict__ col,
                                                    const float* __restrict__ dinv,
                                                    const float* __restrict__ b3,
                                                    float* __restrict__ out) {
    __shared__ int2 tbl[4][64];
    int wv   = threadIdx.x >> 6;
    int lane = threadIdx.x & 63;
    int i = blockIdx.x * 4 + wv;
    if (i >= NN) return;
    int2 se = rr[i];
    int start = se.x, end = se.y;
    float di = dinv[i];
    int og = lane >> 3;          // edge slot 0..7
    int fo = (lane & 7) * 8;     // feature base 0..56
    bool act = fo < KCLS;        // 5 of 8 lanes carry features

    f32x2 a[4];
#pragma unroll
    for (int j = 0; j < 4; j++) { a[j].x = 0.f; a[j].y = 0.f; }
    if (og == 0 && act) {        // self-loop (rows are 80 B = 16B-aligned)
        uint4 v = *(const uint4*)(hb + (size_t)i * KCLS + fo);
        fma8p(v, di * di, a);
    }

    for (int b = start; b < end; b += 64) {
        int n = end - b; if (n > 64) n = 64;
        int2 cw;
        if (lane < n) {
            int c = col[b + lane];
            cw = make_int2(c, __float_as_int(dinv[c] * di));
        } else cw = make_int2(0, 0);
        tbl[wv][lane] = cw;
        __builtin_amdgcn_wave_barrier();
        int tmax = (n + 7) >> 3;
        for (int t = 0; t < tmax; t++) {
            int2 e0 = tbl[wv][8 * t + og];
            if (act) {
                uint4 v0 = *(const uint4*)(hb + (size_t)e0.x * KCLS + fo);
                fma8p(v0, __int_as_float(e0.y), a);
            }
        }
        __builtin_amdgcn_wave_barrier();
    }
    // merge the 8 edge slots
    float x[8];
    x[0]=a[0].x; x[1]=a[0].y; x[2]=a[1].x; x[3]=a[1].y;
    x[4]=a[2].x; x[5]=a[2].y; x[6]=a[3].x; x[7]=a[3].y;
#pragma unroll
    for (int j = 0; j < 8; j++) {
        x[j] += __shfl_xor(x[j], 8);
        x[j] += __shfl_xor(x[j], 16);
        x[j] += __shfl_xor(x[j], 32);
    }

    float v[8];
    if (act) {
        float4 b30 = *(const float4*)(b3 + fo);
        float4 b31 = *(const float4*)(b3 + fo + 4);
        v[0]=x[0]+b30.x; v[1]=x[1]+b30.y; v[2]=x[2]+b30.z; v[3]=x[3]+b30.w;
        v[4]=x[4]+b31.x; v[5]=x[5]+b31.y; v[6]=x[6]+b31.z; v[7]=x[7]+b31.w;
    } else {
#pragma unroll
        for (int j = 0; j < 8; j++) v[j] = -INFINITY;
    }
    float lm = v[0];
#pragma unroll
    for (int j = 1; j < 8; j++) lm = fmaxf(lm, v[j]);
#pragma unroll
    for (int m = 1; m < 8; m <<= 1) lm = fmaxf(lm, __shfl_xor(lm, m));  // max over 8-lane group
    float es = 0.f;
    if (act) {
#pragma unroll
        for (int j = 0; j < 8; j++) es += expf(v[j] - lm);
    }
#pragma unroll
    for (int m = 1; m < 8; m <<= 1) es += __shfl_xor(es, m);
    if (og == 0 && act) {
        float ls = lm + logf(es);
        float4 o0 = make_float4(v[0] - ls, v[1] - ls, v[2] - ls, v[3] - ls);
        float4 o1 = make_float4(v[4] - ls, v[5] - ls, v[6] - ls, v[7] - ls);
        *(float4*)(out + (size_t)i * KCLS + fo) = o0;
        *(float4*)(out + (size_t)i * KCLS + fo + 4) = o1;
    }
}

extern "C" void kernel_launch(void* const* d_in, const int* in_sizes, int n_in,
                              void* d_out, int out_size, void* d_ws, size_t ws_size,
                              hipStream_t stream) {
    const float* x   = (const float*)d_in[0];
    const int*   ei  = (const int*)d_in[1];
    const float* W1  = (const float*)d_in[2];
    const float* b1  = (const float*)d_in[3];
    const float* g1  = (const float*)d_in[4];
    const float* be1 = (const float*)d_in[5];
    const float* W2  = (const float*)d_in[6];
    const float* b2  = (const float*)d_in[7];
    const float* g2  = (const float*)d_in[8];
    const float* be2 = (const float*)d_in[9];
    const float* W3  = (const float*)d_in[10];
    const float* b3  = (const float*)d_in[11];
    const int E = in_sizes[1] / 2;
    const int* srcI = ei;
    const int* dstI = ei + E;

    // workspace (float units):
    // [dinv NN][rr 2NN][btail 512][hbuf NN*64][lbuf NN*64][col NBKT*BSTRIDE]
    // ebuf aliases lbuf (dead until layer-1 gather writes it). GEMM A-tile overrun:
    // hbuf->lbuf, lbuf->col (both allocated).
    float* dinv   = (float*)d_ws;
    int2*  rr     = (int2*)((float*)d_ws + NN);
    int*   btail  = (int*)d_ws + 3 * NN;
    bfu*   hbuf   = (bfu*)((float*)d_ws + 3 * NN + 512);
    bfu*   lbuf   = (bfu*)((float*)d_ws + 3 * NN + 512 + (size_t)NN * 64);
    int*   col    = (int*)d_ws + 3 * NN + 512 + (size_t)NN * 128;
    int*   ebuf   = (int*)lbuf;

    float* out = (float*)d_out;
    dim3 blk(256);

    // ---- CSR build (slack buckets, no global scan) ----
    k_binit<<<(NBKT + 255) / 256, blk, 0, stream>>>(btail);
    k_part<<<(E + PCHUNK - 1) / PCHUNK, blk, 0, stream>>>(srcI, dstI, btail, ebuf, E);
    k_csr<<<NBKT, blk, 0, stream>>>(ebuf, btail, rr, col, dinv);

    const int gx = (NN + 127) / 128;   // 782

    // ---- layer 1 (fp32 A, fused cast) ----
    k_gemm_mfma<128, 128, true><<<gx, blk, 0, stream>>>(x, W1, hbuf, NN);
    k_gather_ln<<<(NN + 3) / 4, blk, 0, stream>>>(hbuf, rr, col, dinv, b1, g1, be1, lbuf);

    // ---- layer 2 ----
    k_gemm_mfma<128, 128, false><<<gx, blk, 0, stream>>>(lbuf, W2, hbuf, NN);
    k_gather_ln<<<(NN + 3) / 4, blk, 0, stream>>>(hbuf, rr, col, dinv, b2, g2, be2, lbuf);

    // ---- layer 3 ----
    k_gemm_mfma<KCLS, 48, false><<<gx, blk, 0, stream>>>(lbuf, W3, hbuf, NN);
    k_gather_lsm<<<(NN + 3) / 4, blk, 0, stream>>>(hbuf, rr, col, dinv, b3, out);
}